// Round 11
// baseline (117.555 us; speedup 1.0000x reference)
//
#include <hip/hip_runtime.h>
#include <math.h>

#define NEGV (-1e9f)

typedef __attribute__((ext_vector_type(8))) short bf16x8;
typedef __attribute__((ext_vector_type(4))) float f32x4;
typedef _Float16 h2 __attribute__((ext_vector_type(2)));
typedef _Float16 h4 __attribute__((ext_vector_type(4)));
typedef _Float16 h8 __attribute__((ext_vector_type(8)));

// ---------------- workspace layout (byte offsets) ----------------
constexpr size_t OFFB_XB   = 0;         // bf16 [3][128][1024]
constexpr size_t OFFB_QB   = 786432;    // bf16 [3][128][1024]
constexpr size_t OFFB_KB   = 1572864;   // bf16 [3][128][1024]
constexpr size_t OFFB_VT   = 2359296;   // bf16 [1024 col][384 tok]  (V transposed)
constexpr size_t OFFB_D0B  = 3145728;   // bf16 [3][128][1024]
constexpr size_t OFFB_D1B  = 3932160;
constexpr size_t OFFB_OB   = 4718592;   // bf16 [3][128][1024] (attn out)
constexpr size_t OFFB_DEC  = 5505024;   // u8 [9][128][128] mask
constexpr size_t OFFB_WFCT = 6094848;   // bf16 [1024][1024]
constexpr size_t OFFB_WQT  = 8192000;
constexpr size_t OFFB_WKT  = 10289152;
constexpr size_t OFFB_WVT  = 12386304;
constexpr size_t OFFB_WD0T = 14483456;
constexpr size_t OFFB_WD1T = 16580608;
constexpr size_t OFFB_W1T  = 18677760;  // bf16 [2048][2048] -> end 27066368
// overlays (lifetime-disjoint):
constexpr size_t OFFB_U1   = OFFB_WQT;             // f16 [3][128][2048] (over wqT/wkT)
constexpr size_t OFFB_U0   = OFFB_WQT + 1572864;   // f16 [3][128][2048]
constexpr size_t OFFB_PART = OFFB_WVT;             // f16 [16][9][128][128] (over wvT+; dead before fc writes O2)
constexpr size_t OFFB_O2   = OFFB_WD1T;            // f32 [3][128][1024]

__device__ __forceinline__ unsigned short f2bf(float f) {
  unsigned int u = __float_as_uint(f);
  unsigned int r = (u + 0x7fffu + ((u >> 16) & 1u)) >> 16;
  return (unsigned short)r;
}
__device__ __forceinline__ float bf2f(unsigned short u) {
  return __uint_as_float(((unsigned int)u) << 16);
}

__device__ __forceinline__ void gload16(const void* g, void* l) {
  __builtin_amdgcn_global_load_lds(
      (const __attribute__((address_space(1))) void*)g,
      (__attribute__((address_space(3))) void*)l, 16, 0, 0);
}

// ---------------- convert + transpose pass ----------------
__global__ __launch_bounds__(256) void convert_kernel(
    const float* __restrict__ x0, const float* __restrict__ x1, const float* __restrict__ x2,
    const float* __restrict__ wq, const float* __restrict__ wk, const float* __restrict__ wv,
    const float* __restrict__ wd0, const float* __restrict__ wd1,
    const float* __restrict__ wfc, const float* __restrict__ w1,
    char* __restrict__ wsb)
{
  const int b = blockIdx.x, tid = threadIdx.x;
  if (b < 192) {
    const int s = b >> 6;
    const int off = (b & 63) * 2048 + tid * 8;
    const float* src = ((s == 0) ? x0 : (s == 1) ? x1 : x2) + off;
    unsigned short* dst = (unsigned short*)(wsb + OFFB_XB) + (size_t)s * 131072 + off;
    float4 v0 = *(const float4*)src;
    float4 v1 = *(const float4*)(src + 4);
    bf16x8 o;
    o[0] = (short)f2bf(v0.x); o[1] = (short)f2bf(v0.y);
    o[2] = (short)f2bf(v0.z); o[3] = (short)f2bf(v0.w);
    o[4] = (short)f2bf(v1.x); o[5] = (short)f2bf(v1.y);
    o[6] = (short)f2bf(v1.z); o[7] = (short)f2bf(v1.w);
    *(bf16x8*)dst = o;
    return;
  }
  __shared__ unsigned short Ls[64][80];
  const float* src;
  unsigned short* dst;
  int dim, tk, tn;
  int bb = b - 192;
  if (bb < 1536) {
    const int wi = bb >> 8, t = bb & 255;
    switch (wi) {
      case 0: src = wq;  dst = (unsigned short*)(wsb + OFFB_WQT);  break;
      case 1: src = wk;  dst = (unsigned short*)(wsb + OFFB_WKT);  break;
      case 2: src = wv;  dst = (unsigned short*)(wsb + OFFB_WVT);  break;
      case 3: src = wd0; dst = (unsigned short*)(wsb + OFFB_WD0T); break;
      case 4: src = wd1; dst = (unsigned short*)(wsb + OFFB_WD1T); break;
      default: src = wfc; dst = (unsigned short*)(wsb + OFFB_WFCT); break;
    }
    dim = 1024; tk = t >> 4; tn = t & 15;
  } else {
    const int t = bb - 1536;
    src = w1; dst = (unsigned short*)(wsb + OFFB_W1T);
    dim = 2048; tk = t >> 5; tn = t & 31;
  }
  const int r = tid >> 2, c0 = (tid & 3) << 4;
  const float* s = src + (size_t)(tk * 64 + r) * dim + tn * 64 + c0;
#pragma unroll
  for (int u = 0; u < 16; u += 4) {
    float4 v = *(const float4*)(s + u);
    Ls[c0 + u + 0][r] = f2bf(v.x);
    Ls[c0 + u + 1][r] = f2bf(v.y);
    Ls[c0 + u + 2][r] = f2bf(v.z);
    Ls[c0 + u + 3][r] = f2bf(v.w);
  }
  __syncthreads();
  unsigned short* d = dst + (size_t)(tn * 64 + r) * dim + tk * 64 + c0;
  *(uint4*)(d) = *(const uint4*)&Ls[r][c0];
  *(uint4*)(d + 8) = *(const uint4*)&Ls[r][c0 + 8];
}

// ---------------- staged MFMA GEMM: C[64 x 64-tile] = A @ BT^T, K=1024 ----------
// 128 threads = 2 waves; 2-deep prefetch with counted vmcnt(8) (T3/T4 minimum).
// mode: 0 = bf16 row, 1 = f32 row, 2 = fp16 row, 3 = bf16 V-transposed
__device__ __forceinline__ void mfma_gemm_db(
    const short* __restrict__ A, int lda,
    const short* __restrict__ BT, int ldb,
    void* __restrict__ out, int ldc,
    const float* __restrict__ bias, int mode)
{
  __shared__ __align__(16) short As[2][4096];   // [64 rows][64 k] swizzled
  __shared__ __align__(16) short Bs[2][4096];   // [64 n][64 k] swizzled
  const int tid = threadIdx.x;
  const int w = tid >> 6, l = tid & 63;
  const int lr = l & 15, lg = l >> 4, sx = lr & 7;
  f32x4 acc[2][4] = {};

  auto stage = [&](int buf, int k0) {
#pragma unroll
    for (int t = 0; t < 4; ++t) {
      const int g = t * 128 + tid;
      const int r = g >> 3;
      const int c16 = (g & 7) ^ (r & 7);
      gload16(A + (size_t)r * lda + k0 + c16 * 8, &As[buf][t * 1024 + w * 512]);
    }
#pragma unroll
    for (int t = 0; t < 4; ++t) {
      const int g = t * 128 + tid;
      const int n = g >> 3;
      const int c16 = (g & 7) ^ (n & 7);
      gload16(BT + (size_t)n * ldb + k0 + c16 * 8, &Bs[buf][t * 1024 + w * 512]);
    }
  };

  stage(0, 0);
  stage(1, 64);
  for (int t = 0; t < 16; ++t) {
    if (t < 15) asm volatile("s_waitcnt vmcnt(8)" ::: "memory");
    else        asm volatile("s_waitcnt vmcnt(0)" ::: "memory");
    __builtin_amdgcn_s_barrier();
    const int cur = t & 1;
#pragma unroll
    for (int kk = 0; kk < 2; ++kk) {
      const int slot = ((kk * 4 + lg) ^ sx) * 8;
      bf16x8 a0 = *(const bf16x8*)&As[cur][(32 * w + lr) * 64 + slot];
      bf16x8 a1 = *(const bf16x8*)&As[cur][(32 * w + 16 + lr) * 64 + slot];
#pragma unroll
      for (int fc = 0; fc < 4; ++fc) {
        bf16x8 b = *(const bf16x8*)&Bs[cur][(16 * fc + lr) * 64 + slot];
        acc[0][fc] = __builtin_amdgcn_mfma_f32_16x16x32_bf16(a0, b, acc[0][fc], 0, 0, 0);
        acc[1][fc] = __builtin_amdgcn_mfma_f32_16x16x32_bf16(a1, b, acc[1][fc], 0, 0, 0);
      }
    }
    __builtin_amdgcn_s_barrier();
    if (t + 2 < 16) stage(cur, (t + 2) * 64);
  }
#pragma unroll
  for (int fr = 0; fr < 2; ++fr)
#pragma unroll
    for (int fc = 0; fc < 4; ++fc)
#pragma unroll
      for (int j = 0; j < 4; ++j) {
        const int row = 32 * w + 16 * fr + lg * 4 + j;
        const int col = 16 * fc + lr;
        float v = acc[fr][fc][j];
        if (bias) v += bias[col];
        if (mode == 0) {
          ((unsigned short*)out)[(size_t)row * ldc + col] = f2bf(v);
        } else if (mode == 1) {
          ((float*)out)[(size_t)row * ldc + col] = v;
        } else if (mode == 2) {
          ((unsigned short*)out)[(size_t)row * ldc + col] =
              __builtin_bit_cast(unsigned short, (_Float16)v);
        } else {
          ((unsigned short*)out)[(size_t)col * 384 + row] = f2bf(v);
        }
      }
}

// grid (16 n, 2 m, 15 z = s*5+wi), 128 threads
__global__ __launch_bounds__(128) void proj_mfma(char* __restrict__ wsb)
{
  const int n0 = blockIdx.x * 64;
  const int m0 = blockIdx.y * 64;
  const int z = blockIdx.z;
  const int s = z / 5, wi = z % 5;
  size_t wtoff;
  switch (wi) {
    case 0:  wtoff = OFFB_WQT;  break;
    case 1:  wtoff = OFFB_WKT;  break;
    case 2:  wtoff = OFFB_WVT;  break;
    case 3:  wtoff = OFFB_WD0T; break;
    default: wtoff = OFFB_WD1T; break;
  }
  const short* A  = (const short*)(wsb + OFFB_XB) + (size_t)s * 131072 + (size_t)m0 * 1024;
  const short* BT = (const short*)(wsb + wtoff) + (size_t)n0 * 1024;
  if (wi == 2) {
    unsigned short* vt = (unsigned short*)(wsb + OFFB_VT) + (size_t)n0 * 384 + s * 128 + m0;
    mfma_gemm_db(A, 1024, BT, 1024, vt, 384, nullptr, 3);
  } else {
    size_t coff = (wi == 0) ? OFFB_QB : (wi == 1) ? OFFB_KB : (wi == 3) ? OFFB_D0B : OFFB_D1B;
    unsigned short* Cb = (unsigned short*)(wsb + coff) + (size_t)s * 131072 +
                         (size_t)m0 * 1024 + n0;
    mfma_gemm_db(A, 1024, BT, 1024, Cb, 1024, nullptr, 0);
  }
}

// grid (32 n, 2 m, 6 z = which*3+s), 128 threads
__global__ __launch_bounds__(128) void u_mfma(const float* __restrict__ b1, char* __restrict__ wsb)
{
  const int n0 = blockIdx.x * 64;
  const int m0 = blockIdx.y * 64;
  const int z = blockIdx.z;
  const int which = z / 3, s = z % 3;
  const short* A = (const short*)(wsb + (which == 0 ? OFFB_D1B : OFFB_D0B)) +
                   (size_t)s * 131072 + (size_t)m0 * 1024;
  const short* BT = (const short*)(wsb + OFFB_W1T) + (size_t)n0 * 2048 + which * 1024;
  unsigned short* Ch = (unsigned short*)(wsb + (which == 0 ? OFFB_U1 : OFFB_U0)) +
                       (size_t)s * 262144 + (size_t)m0 * 2048 + n0;
  const float* bias = (which == 0) ? (b1 + n0) : nullptr;
  mfma_gemm_db(A, 1024, BT, 2048, Ch, 2048, bias, 2);
}

// grid (16 n, 2 m, 3 s), 128 threads
__global__ __launch_bounds__(128) void fc_mfma(char* __restrict__ wsb)
{
  const int n0 = blockIdx.x * 64;
  const int m0 = blockIdx.y * 64;
  const int s = blockIdx.z;
  const short* A = (const short*)(wsb + OFFB_OB) + (size_t)s * 131072 + (size_t)m0 * 1024;
  const short* BT = (const short*)(wsb + OFFB_WFCT) + (size_t)n0 * 1024;
  float* Cf = (float*)(wsb + OFFB_O2) + (size_t)s * 131072 + (size_t)m0 * 1024 + n0;
  mfma_gemm_db(A, 1024, BT, 1024, Cf, 1024, nullptr, 1);
}

// ---------------- decision partials (packed fp16 + v_dot2_f32_f16) ----------------
#define DOT8(ACC, T, W)                                                                        \
  ACC = __builtin_amdgcn_fdot2(__builtin_shufflevector(T, T, 0, 1),                            \
                               __builtin_shufflevector(W, W, 0, 1), ACC, false);               \
  ACC = __builtin_amdgcn_fdot2(__builtin_shufflevector(T, T, 2, 3),                            \
                               __builtin_shufflevector(W, W, 2, 3), ACC, false);               \
  ACC = __builtin_amdgcn_fdot2(__builtin_shufflevector(T, T, 4, 5),                            \
                               __builtin_shufflevector(W, W, 4, 5), ACC, false);               \
  ACC = __builtin_amdgcn_fdot2(__builtin_shufflevector(T, T, 6, 7),                            \
                               __builtin_shufflevector(W, W, 6, 7), ACC, false);

// grid (16 cc, 4 = qt*2+kt, 9 p); block: q64 x k64 x c128, 4x4 micro-tile.
// 9 ds_read_b128 feed 16 relu-dot chains per c8-iter (2x better ratio than 2x4).
__global__ __launch_bounds__(256) void dec_kernel(
    const unsigned short* __restrict__ u1base, const unsigned short* __restrict__ u0base,
    const float* __restrict__ w2, unsigned short* __restrict__ part)
{
  __shared__ unsigned short U1s[64][136];
  __shared__ unsigned short U0s[64][136];
  __shared__ h2 wds[64];
  const int cc = blockIdx.x;
  const int qt = blockIdx.y >> 1, kt = blockIdx.y & 1;
  const int p = blockIdx.z;
  const int i = p / 3, j = p % 3;
  const int q0 = qt * 64, k0 = kt * 64;
  const int cbase = cc * 128;
  const unsigned short* u1 = u1base + (size_t)j * 262144 + (size_t)q0 * 2048 + cbase;
  const unsigned short* u0 = u0base + (size_t)i * 262144 + (size_t)k0 * 2048 + cbase;
  const int tid = threadIdx.x;
  const int ty = tid >> 4, tx = tid & 15;

  {
    const int r = tid >> 2, cg = (tid & 3) << 5;
    const unsigned short* s1 = u1 + (size_t)r * 2048 + cg;
    const unsigned short* s0 = u0 + (size_t)r * 2048 + cg;
#pragma unroll
    for (int t = 0; t < 4; ++t) {
      *(uint4*)&U1s[r][cg + 8 * t] = *(const uint4*)(s1 + 8 * t);
      *(uint4*)&U0s[r][cg + 8 * t] = *(const uint4*)(s0 + 8 * t);
    }
  }
  if (tid < 64) {
    const int c = cbase + tid * 2;
    h2 wv;
    wv[0] = (_Float16)(w2[2 * c + 1] - w2[2 * c]);
    wv[1] = (_Float16)(w2[2 * c + 3] - w2[2 * c + 2]);
    wds[tid] = wv;
  }
  __syncthreads();

  const h8 zero8 = {};
  float acc[4][4] = {};
#pragma unroll
  for (int c8 = 0; c8 < 128; c8 += 8) {
    h8 wv = *(const h8*)&wds[c8 >> 1];
    h8 a0 = *(const h8*)&U1s[ty][c8];
    h8 a1 = *(const h8*)&U1s[ty + 16][c8];
    h8 a2 = *(const h8*)&U1s[ty + 32][c8];
    h8 a3 = *(const h8*)&U1s[ty + 48][c8];
    h8 b0 = *(const h8*)&U0s[tx][c8];
    h8 b1 = *(const h8*)&U0s[tx + 16][c8];
    h8 b2v = *(const h8*)&U0s[tx + 32][c8];
    h8 b3 = *(const h8*)&U0s[tx + 48][c8];
    h8 t;
    t = __builtin_elementwise_max(a0 + b0, zero8);  DOT8(acc[0][0], t, wv);
    t = __builtin_elementwise_max(a0 + b1, zero8);  DOT8(acc[0][1], t, wv);
    t = __builtin_elementwise_max(a0 + b2v, zero8); DOT8(acc[0][2], t, wv);
    t = __builtin_elementwise_max(a0 + b3, zero8);  DOT8(acc[0][3], t, wv);
    t = __builtin_elementwise_max(a1 + b0, zero8);  DOT8(acc[1][0], t, wv);
    t = __builtin_elementwise_max(a1 + b1, zero8);  DOT8(acc[1][1], t, wv);
    t = __builtin_elementwise_max(a1 + b2v, zero8); DOT8(acc[1][2], t, wv);
    t = __builtin_elementwise_max(a1 + b3, zero8);  DOT8(acc[1][3], t, wv);
    t = __builtin_elementwise_max(a2 + b0, zero8);  DOT8(acc[2][0], t, wv);
    t = __builtin_elementwise_max(a2 + b1, zero8);  DOT8(acc[2][1], t, wv);
    t = __builtin_elementwise_max(a2 + b2v, zero8); DOT8(acc[2][2], t, wv);
    t = __builtin_elementwise_max(a2 + b3, zero8);  DOT8(acc[2][3], t, wv);
    t = __builtin_elementwise_max(a3 + b0, zero8);  DOT8(acc[3][0], t, wv);
    t = __builtin_elementwise_max(a3 + b1, zero8);  DOT8(acc[3][1], t, wv);
    t = __builtin_elementwise_max(a3 + b2v, zero8); DOT8(acc[3][2], t, wv);
    t = __builtin_elementwise_max(a3 + b3, zero8);  DOT8(acc[3][3], t, wv);
  }

#pragma unroll
  for (int qi = 0; qi < 4; ++qi)
#pragma unroll
    for (int kj = 0; kj < 4; ++kj) {
      const int q = q0 + ty + 16 * qi;
      const int k = k0 + tx + 16 * kj;
      part[((size_t)cc * 9 + p) * 16384 + (size_t)q * 128 + k] =
          __builtin_bit_cast(unsigned short, (_Float16)acc[qi][kj]);
    }
}

// combine 16 fp16 partials + bias -> byte mask ; grid 144
__global__ __launch_bounds__(256) void combine_kernel(
    const unsigned short* __restrict__ part, const float* __restrict__ b2,
    unsigned char* __restrict__ dec8)
{
  const int idx4 = blockIdx.x * 1024 + threadIdx.x * 4;
  const float bdiff = b2[1] - b2[0];
  float s[4] = {};
#pragma unroll
  for (int c = 0; c < 16; ++c) {
    h4 v = *(const h4*)(part + (size_t)c * 147456 + idx4);
#pragma unroll
    for (int e = 0; e < 4; ++e) s[e] += (float)v[e];
  }
  unsigned int m = 0;
#pragma unroll
  for (int e = 0; e < 4; ++e)
    if (s[e] + bdiff > 0.f) m |= 1u << (8 * e);
  *(unsigned int*)(dec8 + idx4) = m;
}

// ---------------- fused attention: scores + softmax + PV ----------------
// grid (4 qh, 16 h, 3 i), 128 threads = 2 waves; wave owns 16 q rows.
__global__ __launch_bounds__(128) void attn_kernel(
    const unsigned short* __restrict__ Qb, const unsigned short* __restrict__ Kb,
    const unsigned short* __restrict__ VT, const unsigned char* __restrict__ dec8,
    unsigned short* __restrict__ Ob)
{
  __shared__ unsigned short Vls[64][392];
  __shared__ unsigned short Plds[2][16][392];
  const int qh = blockIdx.x, h = blockIdx.y, i = blockIdx.z;
  const int tid = threadIdx.x;
  const int w = tid >> 6, l = tid & 63;
  const int lr = l & 15, lg = l >> 4;

  {
    const unsigned short* src = VT + (size_t)h * 64 * 384;
#pragma unroll
    for (int c = 0; c < 24; ++c) {
      const int g = c * 128 + tid;
      const int row = g / 48, c8 = (g % 48) * 8;
      *(bf16x8*)&Vls[row][c8] = *(const bf16x8*)(src + (size_t)row * 384 + c8);
    }
  }

  const int q0 = qh * 32 + w * 16;
  const unsigned short* qp =
      Qb + (size_t)i * 131072 + (size_t)(q0 + lr) * 1024 + h * 64 + lg * 8;
  bf16x8 aq0 = *(const bf16x8*)qp;
  bf16x8 aq1 = *(const bf16x8*)(qp + 32);

  f32x4 acc[24];
#pragma unroll
  for (int kt = 0; kt < 24; ++kt) acc[kt] = (f32x4){0.f, 0.f, 0.f, 0.f};
#pragma unroll
  for (int kt = 0; kt < 24; ++kt) {
    const int js = kt >> 3;
    const int kk = (kt & 7) * 16 + lr;
    const unsigned short* kp =
        Kb + (size_t)js * 131072 + (size_t)kk * 1024 + h * 64 + lg * 8;
    bf16x8 b0 = *(const bf16x8*)kp;
    bf16x8 b1 = *(const bf16x8*)(kp + 32);
    acc[kt] = __builtin_amdgcn_mfma_f32_16x16x32_bf16(aq0, b0, acc[kt], 0, 0, 0);
    acc[kt] = __builtin_amdgcn_mfma_f32_16x16x32_bf16(aq1, b1, acc[kt], 0, 0, 0);
  }

  float inv[4];
#pragma unroll
  for (int j_ = 0; j_ < 4; ++j_) {
    const int qrow = q0 + lg * 4 + j_;
#pragma unroll
    for (int kt = 0; kt < 24; ++kt) {
      const int p = i * 3 + (kt >> 3);
      const int kcol = (kt & 7) * 16 + lr;
      const unsigned char m = dec8[(size_t)p * 16384 + (size_t)qrow * 128 + kcol];
      acc[kt][j_] = acc[kt][j_] * 0.125f + (m ? NEGV : 0.f);
    }
    float mx = -INFINITY;
#pragma unroll
    for (int kt = 0; kt < 24; ++kt) mx = fmaxf(mx, acc[kt][j_]);
#pragma unroll
    for (int off = 1; off < 16; off <<= 1) mx = fmaxf(mx, __shfl_xor(mx, off));
    float sm = 0.f;
#pragma unroll
    for (int kt = 0; kt < 24; ++kt) {
      acc[kt][j_] = __expf(acc[kt][j_] - mx);
      sm += acc[kt][j_];
    }
#pragma unroll
    for (int off = 1; off < 16; off <<= 1) sm += __shfl_xor(sm, off);
    inv[j_] = 1.f / sm;
  }

#pragma unroll
  for (int kt = 0; kt < 24; ++kt)
#pragma unroll
    for (int j_ = 0; j_ < 4; ++j_)
      Plds[w][lg * 4 + j_][kt * 16 + lr] = f2bf(acc[kt][j_]);
  __syncthreads();

  f32x4 accO[4];
#pragma unroll
  for (int dvt = 0; dvt < 4; ++dvt) accO[dvt] = (f32x4){0.f, 0.f, 0.f, 0.f};
#pragma unroll
  for (int ks = 0; ks < 12; ++ks) {
    bf16x8 a = *(const bf16x8*)&Plds[w][lr][ks * 32 + lg * 8];
#pragma unroll
    for (int dvt = 0; dvt < 4; ++dvt) {
      bf16x8 b = *(const bf16x8*)&Vls[dvt * 16 + lr][ks * 32 + lg * 8];
      accO[dvt] = __builtin_amdgcn_mfma_f32_16x16x32_bf16(a, b, accO[dvt], 0, 0, 0);
    }
  }
#pragma unroll
  for (int dvt = 0; dvt < 4; ++dvt)
#pragma unroll
    for (int j_ = 0; j_ < 4; ++j_) {
      const int qrow = q0 + lg * 4 + j_;
      Ob[(size_t)i * 131072 + (size_t)qrow * 1024 + h * 64 + dvt * 16 + lr] =
          f2bf(accO[dvt][j_] * inv[j_]);
    }
}

// ---------------- LayerNorm(o2 + x) ----------------
__global__ __launch_bounds__(256) void ln_kernel(
    const float* __restrict__ O2, const float* __restrict__ x0,
    const float* __restrict__ x1, const float* __restrict__ x2,
    const float* __restrict__ g, const float* __restrict__ bta,
    float* __restrict__ out)
{
  const int row = blockIdx.x;
  const int i = row >> 7, l = row & 127;
  const float* xr = ((i == 0) ? x0 : (i == 1) ? x1 : x2) + (size_t)l * 1024;
  const float* o2 = O2 + (size_t)i * 131072 + (size_t)l * 1024;
  const int tid = threadIdx.x;
  float4 v = *(const float4*)(o2 + tid * 4);
  const float4 xv = *(const float4*)(xr + tid * 4);
  v.x += xv.x; v.y += xv.y; v.z += xv.z; v.w += xv.w;
  float s = v.x + v.y + v.z + v.w;
  float s2 = v.x * v.x + v.y * v.y + v.z * v.z + v.w * v.w;
#pragma unroll
  for (int off = 32; off; off >>= 1) {
    s += __shfl_xor(s, off);
    s2 += __shfl_xor(s2, off);
  }
  __shared__ float red[2][4];
  const int wave = tid >> 6, lane = tid & 63;
  if (lane == 0) { red[0][wave] = s; red[1][wave] = s2; }
  __syncthreads();
  s = red[0][0] + red[0][1] + red[0][2] + red[0][3];
  s2 = red[1][0] + red[1][1] + red[1][2] + red[1][3];
  const float mu = s * (1.f / 1024.f);
  const float var = s2 * (1.f / 1024.f) - mu * mu;
  const float rstd = rsqrtf(var + 1e-6f);
  const float4 gv = *(const float4*)(g + tid * 4);
  const float4 bv = *(const float4*)(bta + tid * 4);
  float4 o;
  o.x = (v.x - mu) * rstd * gv.x + bv.x;
  o.y = (v.y - mu) * rstd * gv.y + bv.y;
  o.z = (v.z - mu) * rstd * gv.z + bv.z;
  o.w = (v.w - mu) * rstd * gv.w + bv.w;
  *(float4*)(out + (size_t)row * 1024 + tid * 4) = o;
}

extern "C" void kernel_launch(void* const* d_in, const int* in_sizes, int n_in,
                              void* d_out, int out_size, void* d_ws, size_t ws_size,
                              hipStream_t stream)
{
  const float* x0  = (const float*)d_in[0];
  const float* x1  = (const float*)d_in[1];
  const float* x2  = (const float*)d_in[2];
  const float* wq  = (const float*)d_in[3];
  const float* wk  = (const float*)d_in[4];
  const float* wv  = (const float*)d_in[5];
  const float* wfc = (const float*)d_in[6];
  const float* wd0 = (const float*)d_in[7];
  const float* wd1 = (const float*)d_in[8];
  const float* w1  = (const float*)d_in[9];
  const float* b1  = (const float*)d_in[10];
  const float* w2  = (const float*)d_in[11];
  const float* b2  = (const float*)d_in[12];
  const float* lng = (const float*)d_in[13];
  const float* lnb = (const float*)d_in[14];
  char* wsb = (char*)d_ws;
  float* out = (float*)d_out;

  convert_kernel<<<2752, 256, 0, stream>>>(x0, x1, x2, wq, wk, wv, wd0, wd1, wfc, w1, wsb);
  proj_mfma<<<dim3(16, 2, 15), 128, 0, stream>>>(wsb);
  u_mfma<<<dim3(32, 2, 6), 128, 0, stream>>>(b1, wsb);
  dec_kernel<<<dim3(16, 4, 9), 256, 0, stream>>>(
      (const unsigned short*)(wsb + OFFB_U1), (const unsigned short*)(wsb + OFFB_U0), w2,
      (unsigned short*)(wsb + OFFB_PART));
  combine_kernel<<<144, 256, 0, stream>>>(
      (const unsigned short*)(wsb + OFFB_PART), b2, (unsigned char*)(wsb + OFFB_DEC));
  attn_kernel<<<dim3(4, 16, 3), 128, 0, stream>>>(
      (const unsigned short*)(wsb + OFFB_QB), (const unsigned short*)(wsb + OFFB_KB),
      (const unsigned short*)(wsb + OFFB_VT), (const unsigned char*)(wsb + OFFB_DEC),
      (unsigned short*)(wsb + OFFB_OB));
  fc_mfma<<<dim3(16, 2, 3), 128, 0, stream>>>(wsb);
  ln_kernel<<<384, 256, 0, stream>>>((const float*)(wsb + OFFB_O2), x0, x1, x2,
                                     lng, lnb, out);
}

// Round 12
// 89.092 us; speedup vs baseline: 1.3195x; 1.3195x over previous
//
#include <hip/hip_runtime.h>
#include <math.h>

#define NEGV (-1e9f)

typedef __attribute__((ext_vector_type(8))) short bf16x8;
typedef __attribute__((ext_vector_type(4))) float f32x4;
typedef _Float16 h2 __attribute__((ext_vector_type(2)));
typedef _Float16 h4 __attribute__((ext_vector_type(4)));
typedef _Float16 h8 __attribute__((ext_vector_type(8)));

// ---------------- workspace layout (byte offsets) ----------------
constexpr size_t OFFB_XB   = 0;         // bf16 [3][128][1024]
constexpr size_t OFFB_QB   = 786432;    // bf16 [3][128][1024]
constexpr size_t OFFB_KB   = 1572864;   // bf16 [3][128][1024]
constexpr size_t OFFB_VT   = 2359296;   // bf16 [1024 col][384 tok]  (V transposed)
constexpr size_t OFFB_D0B  = 3145728;   // bf16 [3][128][1024]
constexpr size_t OFFB_D1B  = 3932160;
constexpr size_t OFFB_OB   = 4718592;   // bf16 [3][128][1024] (attn out)
constexpr size_t OFFB_DEC  = 5505024;   // u8 [9][128][128] mask
constexpr size_t OFFB_WFCT = 6094848;   // bf16 [1024][1024]
constexpr size_t OFFB_WQT  = 8192000;
constexpr size_t OFFB_WKT  = 10289152;
constexpr size_t OFFB_WVT  = 12386304;
constexpr size_t OFFB_WD0T = 14483456;
constexpr size_t OFFB_WD1T = 16580608;
constexpr size_t OFFB_W1T  = 18677760;  // bf16 [2048][2048] -> end 27066368
// overlays (lifetime-disjoint):
constexpr size_t OFFB_U1   = OFFB_WQT;             // f16 [3][128][2048] (over wqT/wkT)
constexpr size_t OFFB_U0   = OFFB_WQT + 1572864;   // f16 [3][128][2048]
constexpr size_t OFFB_PART = OFFB_WVT;             // f16 [32][9][128][128] (over wvT/wd0T/wd1T/w1T-start; all dead after u_mfma)
constexpr size_t OFFB_O2   = OFFB_WD1T;            // f32 [3][128][1024] (written by fc after PART dead)

__device__ __forceinline__ unsigned short f2bf(float f) {
  unsigned int u = __float_as_uint(f);
  unsigned int r = (u + 0x7fffu + ((u >> 16) & 1u)) >> 16;
  return (unsigned short)r;
}
__device__ __forceinline__ float bf2f(unsigned short u) {
  return __uint_as_float(((unsigned int)u) << 16);
}

__device__ __forceinline__ void gload16(const void* g, void* l) {
  __builtin_amdgcn_global_load_lds(
      (const __attribute__((address_space(1))) void*)g,
      (__attribute__((address_space(3))) void*)l, 16, 0, 0);
}

// ---------------- convert + transpose pass ----------------
__global__ __launch_bounds__(256) void convert_kernel(
    const float* __restrict__ x0, const float* __restrict__ x1, const float* __restrict__ x2,
    const float* __restrict__ wq, const float* __restrict__ wk, const float* __restrict__ wv,
    const float* __restrict__ wd0, const float* __restrict__ wd1,
    const float* __restrict__ wfc, const float* __restrict__ w1,
    char* __restrict__ wsb)
{
  const int b = blockIdx.x, tid = threadIdx.x;
  if (b < 192) {
    const int s = b >> 6;
    const int off = (b & 63) * 2048 + tid * 8;
    const float* src = ((s == 0) ? x0 : (s == 1) ? x1 : x2) + off;
    unsigned short* dst = (unsigned short*)(wsb + OFFB_XB) + (size_t)s * 131072 + off;
    float4 v0 = *(const float4*)src;
    float4 v1 = *(const float4*)(src + 4);
    bf16x8 o;
    o[0] = (short)f2bf(v0.x); o[1] = (short)f2bf(v0.y);
    o[2] = (short)f2bf(v0.z); o[3] = (short)f2bf(v0.w);
    o[4] = (short)f2bf(v1.x); o[5] = (short)f2bf(v1.y);
    o[6] = (short)f2bf(v1.z); o[7] = (short)f2bf(v1.w);
    *(bf16x8*)dst = o;
    return;
  }
  __shared__ unsigned short Ls[64][80];
  const float* src;
  unsigned short* dst;
  int dim, tk, tn;
  int bb = b - 192;
  if (bb < 1536) {
    const int wi = bb >> 8, t = bb & 255;
    switch (wi) {
      case 0: src = wq;  dst = (unsigned short*)(wsb + OFFB_WQT);  break;
      case 1: src = wk;  dst = (unsigned short*)(wsb + OFFB_WKT);  break;
      case 2: src = wv;  dst = (unsigned short*)(wsb + OFFB_WVT);  break;
      case 3: src = wd0; dst = (unsigned short*)(wsb + OFFB_WD0T); break;
      case 4: src = wd1; dst = (unsigned short*)(wsb + OFFB_WD1T); break;
      default: src = wfc; dst = (unsigned short*)(wsb + OFFB_WFCT); break;
    }
    dim = 1024; tk = t >> 4; tn = t & 15;
  } else {
    const int t = bb - 1536;
    src = w1; dst = (unsigned short*)(wsb + OFFB_W1T);
    dim = 2048; tk = t >> 5; tn = t & 31;
  }
  const int r = tid >> 2, c0 = (tid & 3) << 4;
  const float* s = src + (size_t)(tk * 64 + r) * dim + tn * 64 + c0;
#pragma unroll
  for (int u = 0; u < 16; u += 4) {
    float4 v = *(const float4*)(s + u);
    Ls[c0 + u + 0][r] = f2bf(v.x);
    Ls[c0 + u + 1][r] = f2bf(v.y);
    Ls[c0 + u + 2][r] = f2bf(v.z);
    Ls[c0 + u + 3][r] = f2bf(v.w);
  }
  __syncthreads();
  unsigned short* d = dst + (size_t)(tn * 64 + r) * dim + tk * 64 + c0;
  *(uint4*)(d) = *(const uint4*)&Ls[r][c0];
  *(uint4*)(d + 8) = *(const uint4*)&Ls[r][c0 + 8];
}

// ---------------- staged MFMA GEMM: C[64 x 64-tile] = A @ BT^T, K=1024 ----------
// 128 threads = 2 waves; 2-deep prefetch with counted vmcnt(8) (T3/T4 minimum).
// mode: 0 = bf16 row, 1 = f32 row, 2 = fp16 row, 3 = bf16 V-transposed
__device__ __forceinline__ void mfma_gemm_db(
    const short* __restrict__ A, int lda,
    const short* __restrict__ BT, int ldb,
    void* __restrict__ out, int ldc,
    const float* __restrict__ bias, int mode)
{
  __shared__ __align__(16) short As[2][4096];   // [64 rows][64 k] swizzled
  __shared__ __align__(16) short Bs[2][4096];   // [64 n][64 k] swizzled
  const int tid = threadIdx.x;
  const int w = tid >> 6, l = tid & 63;
  const int lr = l & 15, lg = l >> 4, sx = lr & 7;
  f32x4 acc[2][4] = {};

  auto stage = [&](int buf, int k0) {
#pragma unroll
    for (int t = 0; t < 4; ++t) {
      const int g = t * 128 + tid;
      const int r = g >> 3;
      const int c16 = (g & 7) ^ (r & 7);
      gload16(A + (size_t)r * lda + k0 + c16 * 8, &As[buf][t * 1024 + w * 512]);
    }
#pragma unroll
    for (int t = 0; t < 4; ++t) {
      const int g = t * 128 + tid;
      const int n = g >> 3;
      const int c16 = (g & 7) ^ (n & 7);
      gload16(BT + (size_t)n * ldb + k0 + c16 * 8, &Bs[buf][t * 1024 + w * 512]);
    }
  };

  stage(0, 0);
  stage(1, 64);
  for (int t = 0; t < 16; ++t) {
    if (t < 15) asm volatile("s_waitcnt vmcnt(8)" ::: "memory");
    else        asm volatile("s_waitcnt vmcnt(0)" ::: "memory");
    __builtin_amdgcn_s_barrier();
    const int cur = t & 1;
#pragma unroll
    for (int kk = 0; kk < 2; ++kk) {
      const int slot = ((kk * 4 + lg) ^ sx) * 8;
      bf16x8 a0 = *(const bf16x8*)&As[cur][(32 * w + lr) * 64 + slot];
      bf16x8 a1 = *(const bf16x8*)&As[cur][(32 * w + 16 + lr) * 64 + slot];
#pragma unroll
      for (int fc = 0; fc < 4; ++fc) {
        bf16x8 b = *(const bf16x8*)&Bs[cur][(16 * fc + lr) * 64 + slot];
        acc[0][fc] = __builtin_amdgcn_mfma_f32_16x16x32_bf16(a0, b, acc[0][fc], 0, 0, 0);
        acc[1][fc] = __builtin_amdgcn_mfma_f32_16x16x32_bf16(a1, b, acc[1][fc], 0, 0, 0);
      }
    }
    __builtin_amdgcn_s_barrier();
    if (t + 2 < 16) stage(cur, (t + 2) * 64);
  }
#pragma unroll
  for (int fr = 0; fr < 2; ++fr)
#pragma unroll
    for (int fc = 0; fc < 4; ++fc)
#pragma unroll
      for (int j = 0; j < 4; ++j) {
        const int row = 32 * w + 16 * fr + lg * 4 + j;
        const int col = 16 * fc + lr;
        float v = acc[fr][fc][j];
        if (bias) v += bias[col];
        if (mode == 0) {
          ((unsigned short*)out)[(size_t)row * ldc + col] = f2bf(v);
        } else if (mode == 1) {
          ((float*)out)[(size_t)row * ldc + col] = v;
        } else if (mode == 2) {
          ((unsigned short*)out)[(size_t)row * ldc + col] =
              __builtin_bit_cast(unsigned short, (_Float16)v);
        } else {
          ((unsigned short*)out)[(size_t)col * 384 + row] = f2bf(v);
        }
      }
}

// grid (16 n, 2 m, 15 z = s*5+wi), 128 threads
__global__ __launch_bounds__(128) void proj_mfma(char* __restrict__ wsb)
{
  const int n0 = blockIdx.x * 64;
  const int m0 = blockIdx.y * 64;
  const int z = blockIdx.z;
  const int s = z / 5, wi = z % 5;
  size_t wtoff;
  switch (wi) {
    case 0:  wtoff = OFFB_WQT;  break;
    case 1:  wtoff = OFFB_WKT;  break;
    case 2:  wtoff = OFFB_WVT;  break;
    case 3:  wtoff = OFFB_WD0T; break;
    default: wtoff = OFFB_WD1T; break;
  }
  const short* A  = (const short*)(wsb + OFFB_XB) + (size_t)s * 131072 + (size_t)m0 * 1024;
  const short* BT = (const short*)(wsb + wtoff) + (size_t)n0 * 1024;
  if (wi == 2) {
    unsigned short* vt = (unsigned short*)(wsb + OFFB_VT) + (size_t)n0 * 384 + s * 128 + m0;
    mfma_gemm_db(A, 1024, BT, 1024, vt, 384, nullptr, 3);
  } else {
    size_t coff = (wi == 0) ? OFFB_QB : (wi == 1) ? OFFB_KB : (wi == 3) ? OFFB_D0B : OFFB_D1B;
    unsigned short* Cb = (unsigned short*)(wsb + coff) + (size_t)s * 131072 +
                         (size_t)m0 * 1024 + n0;
    mfma_gemm_db(A, 1024, BT, 1024, Cb, 1024, nullptr, 0);
  }
}

// grid (32 n, 2 m, 6 z = which*3+s), 128 threads
__global__ __launch_bounds__(128) void u_mfma(const float* __restrict__ b1, char* __restrict__ wsb)
{
  const int n0 = blockIdx.x * 64;
  const int m0 = blockIdx.y * 64;
  const int z = blockIdx.z;
  const int which = z / 3, s = z % 3;
  const short* A = (const short*)(wsb + (which == 0 ? OFFB_D1B : OFFB_D0B)) +
                   (size_t)s * 131072 + (size_t)m0 * 1024;
  const short* BT = (const short*)(wsb + OFFB_W1T) + (size_t)n0 * 2048 + which * 1024;
  unsigned short* Ch = (unsigned short*)(wsb + (which == 0 ? OFFB_U1 : OFFB_U0)) +
                       (size_t)s * 262144 + (size_t)m0 * 2048 + n0;
  const float* bias = (which == 0) ? (b1 + n0) : nullptr;
  mfma_gemm_db(A, 1024, BT, 2048, Ch, 2048, bias, 2);
}

// grid (16 n, 2 m, 3 s), 128 threads
__global__ __launch_bounds__(128) void fc_mfma(char* __restrict__ wsb)
{
  const int n0 = blockIdx.x * 64;
  const int m0 = blockIdx.y * 64;
  const int s = blockIdx.z;
  const short* A = (const short*)(wsb + OFFB_OB) + (size_t)s * 131072 + (size_t)m0 * 1024;
  const short* BT = (const short*)(wsb + OFFB_WFCT) + (size_t)n0 * 1024;
  float* Cf = (float*)(wsb + OFFB_O2) + (size_t)s * 131072 + (size_t)m0 * 1024 + n0;
  mfma_gemm_db(A, 1024, BT, 1024, Cf, 1024, nullptr, 1);
}

// ---------------- decision partials (packed fp16 + v_dot2_f32_f16) ----------------
#define DOT8(ACC, T, W)                                                                        \
  ACC = __builtin_amdgcn_fdot2(__builtin_shufflevector(T, T, 0, 1),                            \
                               __builtin_shufflevector(W, W, 0, 1), ACC, false);               \
  ACC = __builtin_amdgcn_fdot2(__builtin_shufflevector(T, T, 2, 3),                            \
                               __builtin_shufflevector(W, W, 2, 3), ACC, false);               \
  ACC = __builtin_amdgcn_fdot2(__builtin_shufflevector(T, T, 4, 5),                            \
                               __builtin_shufflevector(W, W, 4, 5), ACC, false);               \
  ACC = __builtin_amdgcn_fdot2(__builtin_shufflevector(T, T, 6, 7),                            \
                               __builtin_shufflevector(W, W, 6, 7), ACC, false);

// grid (32 cc, 8 = qt*2+kt, 9 p); block: q32 x k64 x c64, single stage.
// r9's exact 2x4 micro-structure, channels split 2x finer again for max TLP.
__global__ __launch_bounds__(256) void dec_kernel(
    const unsigned short* __restrict__ u1base, const unsigned short* __restrict__ u0base,
    const float* __restrict__ w2, unsigned short* __restrict__ part)
{
  __shared__ unsigned short U1s[32][72];
  __shared__ unsigned short U0s[64][72];
  __shared__ h2 wds[32];
  const int cc = blockIdx.x;
  const int qt = blockIdx.y >> 1, kt = blockIdx.y & 1;
  const int p = blockIdx.z;
  const int i = p / 3, j = p % 3;
  const int q0 = qt * 32, k0 = kt * 64;
  const int cbase = cc * 64;
  const unsigned short* u1 = u1base + (size_t)j * 262144 + (size_t)q0 * 2048 + cbase;
  const unsigned short* u0 = u0base + (size_t)i * 262144 + (size_t)k0 * 2048 + cbase;
  const int tid = threadIdx.x;
  const int ty = tid >> 4, tx = tid & 15;

  {
    const int r = tid >> 3, c8 = (tid & 7) << 3;
    *(uint4*)&U1s[r][c8] = *(const uint4*)(u1 + (size_t)r * 2048 + c8);
  }
#pragma unroll
  for (int t = 0; t < 2; ++t) {
    const int g = tid + t * 256;
    const int r = g >> 3, c8 = (g & 7) << 3;
    *(uint4*)&U0s[r][c8] = *(const uint4*)(u0 + (size_t)r * 2048 + c8);
  }
  if (tid < 32) {
    const int c = cbase + tid * 2;
    h2 wv;
    wv[0] = (_Float16)(w2[2 * c + 1] - w2[2 * c]);
    wv[1] = (_Float16)(w2[2 * c + 3] - w2[2 * c + 2]);
    wds[tid] = wv;
  }
  __syncthreads();

  const h8 zero8 = {};
  float acc[2][4] = {};
#pragma unroll
  for (int c8 = 0; c8 < 64; c8 += 8) {
    h8 wv = *(const h8*)&wds[c8 >> 1];
    h8 a0 = *(const h8*)&U1s[ty][c8];
    h8 a1 = *(const h8*)&U1s[ty + 16][c8];
    h8 b0 = *(const h8*)&U0s[tx][c8];
    h8 b1 = *(const h8*)&U0s[tx + 16][c8];
    h8 b2v = *(const h8*)&U0s[tx + 32][c8];
    h8 b3 = *(const h8*)&U0s[tx + 48][c8];
    h8 t;
    t = __builtin_elementwise_max(a0 + b0, zero8);  DOT8(acc[0][0], t, wv);
    t = __builtin_elementwise_max(a0 + b1, zero8);  DOT8(acc[0][1], t, wv);
    t = __builtin_elementwise_max(a0 + b2v, zero8); DOT8(acc[0][2], t, wv);
    t = __builtin_elementwise_max(a0 + b3, zero8);  DOT8(acc[0][3], t, wv);
    t = __builtin_elementwise_max(a1 + b0, zero8);  DOT8(acc[1][0], t, wv);
    t = __builtin_elementwise_max(a1 + b1, zero8);  DOT8(acc[1][1], t, wv);
    t = __builtin_elementwise_max(a1 + b2v, zero8); DOT8(acc[1][2], t, wv);
    t = __builtin_elementwise_max(a1 + b3, zero8);  DOT8(acc[1][3], t, wv);
  }

#pragma unroll
  for (int qi = 0; qi < 2; ++qi)
#pragma unroll
    for (int kj = 0; kj < 4; ++kj) {
      const int q = q0 + ty + 16 * qi;
      const int k = k0 + tx + 16 * kj;
      part[((size_t)cc * 9 + p) * 16384 + (size_t)q * 128 + k] =
          __builtin_bit_cast(unsigned short, (_Float16)acc[qi][kj]);
    }
}

// combine 32 fp16 partials + bias -> byte mask ; grid 144
__global__ __launch_bounds__(256) void combine_kernel(
    const unsigned short* __restrict__ part, const float* __restrict__ b2,
    unsigned char* __restrict__ dec8)
{
  const int idx4 = blockIdx.x * 1024 + threadIdx.x * 4;
  const float bdiff = b2[1] - b2[0];
  float s[4] = {};
#pragma unroll
  for (int c = 0; c < 32; ++c) {
    h4 v = *(const h4*)(part + (size_t)c * 147456 + idx4);
#pragma unroll
    for (int e = 0; e < 4; ++e) s[e] += (float)v[e];
  }
  unsigned int m = 0;
#pragma unroll
  for (int e = 0; e < 4; ++e)
    if (s[e] + bdiff > 0.f) m |= 1u << (8 * e);
  *(unsigned int*)(dec8 + idx4) = m;
}

// ---------------- fused attention: scores + softmax + PV ----------------
// grid (4 qh, 16 h, 3 i), 128 threads = 2 waves; wave owns 16 q rows.
__global__ __launch_bounds__(128) void attn_kernel(
    const unsigned short* __restrict__ Qb, const unsigned short* __restrict__ Kb,
    const unsigned short* __restrict__ VT, const unsigned char* __restrict__ dec8,
    unsigned short* __restrict__ Ob)
{
  __shared__ unsigned short Vls[64][392];
  __shared__ unsigned short Plds[2][16][392];
  const int qh = blockIdx.x, h = blockIdx.y, i = blockIdx.z;
  const int tid = threadIdx.x;
  const int w = tid >> 6, l = tid & 63;
  const int lr = l & 15, lg = l >> 4;

  {
    const unsigned short* src = VT + (size_t)h * 64 * 384;
#pragma unroll
    for (int c = 0; c < 24; ++c) {
      const int g = c * 128 + tid;
      const int row = g / 48, c8 = (g % 48) * 8;
      *(bf16x8*)&Vls[row][c8] = *(const bf16x8*)(src + (size_t)row * 384 + c8);
    }
  }

  const int q0 = qh * 32 + w * 16;
  const unsigned short* qp =
      Qb + (size_t)i * 131072 + (size_t)(q0 + lr) * 1024 + h * 64 + lg * 8;
  bf16x8 aq0 = *(const bf16x8*)qp;
  bf16x8 aq1 = *(const bf16x8*)(qp + 32);

  f32x4 acc[24];
#pragma unroll
  for (int kt = 0; kt < 24; ++kt) acc[kt] = (f32x4){0.f, 0.f, 0.f, 0.f};
#pragma unroll
  for (int kt = 0; kt < 24; ++kt) {
    const int js = kt >> 3;
    const int kk = (kt & 7) * 16 + lr;
    const unsigned short* kp =
        Kb + (size_t)js * 131072 + (size_t)kk * 1024 + h * 64 + lg * 8;
    bf16x8 b0 = *(const bf16x8*)kp;
    bf16x8 b1 = *(const bf16x8*)(kp + 32);
    acc[kt] = __builtin_amdgcn_mfma_f32_16x16x32_bf16(aq0, b0, acc[kt], 0, 0, 0);
    acc[kt] = __builtin_amdgcn_mfma_f32_16x16x32_bf16(aq1, b1, acc[kt], 0, 0, 0);
  }

  float inv[4];
#pragma unroll
  for (int j_ = 0; j_ < 4; ++j_) {
    const int qrow = q0 + lg * 4 + j_;
#pragma unroll
    for (int kt = 0; kt < 24; ++kt) {
      const int p = i * 3 + (kt >> 3);
      const int kcol = (kt & 7) * 16 + lr;
      const unsigned char m = dec8[(size_t)p * 16384 + (size_t)qrow * 128 + kcol];
      acc[kt][j_] = acc[kt][j_] * 0.125f + (m ? NEGV : 0.f);
    }
    float mx = -INFINITY;
#pragma unroll
    for (int kt = 0; kt < 24; ++kt) mx = fmaxf(mx, acc[kt][j_]);
#pragma unroll
    for (int off = 1; off < 16; off <<= 1) mx = fmaxf(mx, __shfl_xor(mx, off));
    float sm = 0.f;
#pragma unroll
    for (int kt = 0; kt < 24; ++kt) {
      acc[kt][j_] = __expf(acc[kt][j_] - mx);
      sm += acc[kt][j_];
    }
#pragma unroll
    for (int off = 1; off < 16; off <<= 1) sm += __shfl_xor(sm, off);
    inv[j_] = 1.f / sm;
  }

#pragma unroll
  for (int kt = 0; kt < 24; ++kt)
#pragma unroll
    for (int j_ = 0; j_ < 4; ++j_)
      Plds[w][lg * 4 + j_][kt * 16 + lr] = f2bf(acc[kt][j_]);
  __syncthreads();

  f32x4 accO[4];
#pragma unroll
  for (int dvt = 0; dvt < 4; ++dvt) accO[dvt] = (f32x4){0.f, 0.f, 0.f, 0.f};
#pragma unroll
  for (int ks = 0; ks < 12; ++ks) {
    bf16x8 a = *(const bf16x8*)&Plds[w][lr][ks * 32 + lg * 8];
#pragma unroll
    for (int dvt = 0; dvt < 4; ++dvt) {
      bf16x8 b = *(const bf16x8*)&Vls[dvt * 16 + lr][ks * 32 + lg * 8];
      accO[dvt] = __builtin_amdgcn_mfma_f32_16x16x32_bf16(a, b, accO[dvt], 0, 0, 0);
    }
  }
#pragma unroll
  for (int dvt = 0; dvt < 4; ++dvt)
#pragma unroll
    for (int j_ = 0; j_ < 4; ++j_) {
      const int qrow = q0 + lg * 4 + j_;
      Ob[(size_t)i * 131072 + (size_t)qrow * 1024 + h * 64 + dvt * 16 + lr] =
          f2bf(accO[dvt][j_] * inv[j_]);
    }
}

// ---------------- LayerNorm(o2 + x) ----------------
__global__ __launch_bounds__(256) void ln_kernel(
    const float* __restrict__ O2, const float* __restrict__ x0,
    const float* __restrict__ x1, const float* __restrict__ x2,
    const float* __restrict__ g, const float* __restrict__ bta,
    float* __restrict__ out)
{
  const int row = blockIdx.x;
  const int i = row >> 7, l = row & 127;
  const float* xr = ((i == 0) ? x0 : (i == 1) ? x1 : x2) + (size_t)l * 1024;
  const float* o2 = O2 + (size_t)i * 131072 + (size_t)l * 1024;
  const int tid = threadIdx.x;
  float4 v = *(const float4*)(o2 + tid * 4);
  const float4 xv = *(const float4*)(xr + tid * 4);
  v.x += xv.x; v.y += xv.y; v.z += xv.z; v.w += xv.w;
  float s = v.x + v.y + v.z + v.w;
  float s2 = v.x * v.x + v.y * v.y + v.z * v.z + v.w * v.w;
#pragma unroll
  for (int off = 32; off; off >>= 1) {
    s += __shfl_xor(s, off);
    s2 += __shfl_xor(s2, off);
  }
  __shared__ float red[2][4];
  const int wave = tid >> 6, lane = tid & 63;
  if (lane == 0) { red[0][wave] = s; red[1][wave] = s2; }
  __syncthreads();
  s = red[0][0] + red[0][1] + red[0][2] + red[0][3];
  s2 = red[1][0] + red[1][1] + red[1][2] + red[1][3];
  const float mu = s * (1.f / 1024.f);
  const float var = s2 * (1.f / 1024.f) - mu * mu;
  const float rstd = rsqrtf(var + 1e-6f);
  const float4 gv = *(const float4*)(g + tid * 4);
  const float4 bv = *(const float4*)(bta + tid * 4);
  float4 o;
  o.x = (v.x - mu) * rstd * gv.x + bv.x;
  o.y = (v.y - mu) * rstd * gv.y + bv.y;
  o.z = (v.z - mu) * rstd * gv.z + bv.z;
  o.w = (v.w - mu) * rstd * gv.w + bv.w;
  *(float4*)(out + (size_t)row * 1024 + tid * 4) = o;
}

extern "C" void kernel_launch(void* const* d_in, const int* in_sizes, int n_in,
                              void* d_out, int out_size, void* d_ws, size_t ws_size,
                              hipStream_t stream)
{
  const float* x0  = (const float*)d_in[0];
  const float* x1  = (const float*)d_in[1];
  const float* x2  = (const float*)d_in[2];
  const float* wq  = (const float*)d_in[3];
  const float* wk  = (const float*)d_in[4];
  const float* wv  = (const float*)d_in[5];
  const float* wfc = (const float*)d_in[6];
  const float* wd0 = (const float*)d_in[7];
  const float* wd1 = (const float*)d_in[8];
  const float* w1  = (const float*)d_in[9];
  const float* b1  = (const float*)d_in[10];
  const float* w2  = (const float*)d_in[11];
  const float* b2  = (const float*)d_in[12];
  const float* lng = (const float*)d_in[13];
  const float* lnb = (const float*)d_in[14];
  char* wsb = (char*)d_ws;
  float* out = (float*)d_out;

  convert_kernel<<<2752, 256, 0, stream>>>(x0, x1, x2, wq, wk, wv, wd0, wd1, wfc, w1, wsb);
  proj_mfma<<<dim3(16, 2, 15), 128, 0, stream>>>(wsb);
  u_mfma<<<dim3(32, 2, 6), 128, 0, stream>>>(b1, wsb);
  dec_kernel<<<dim3(32, 8, 9), 256, 0, stream>>>(
      (const unsigned short*)(wsb + OFFB_U1), (const unsigned short*)(wsb + OFFB_U0), w2,
      (unsigned short*)(wsb + OFFB_PART));
  combine_kernel<<<144, 256, 0, stream>>>(
      (const unsigned short*)(wsb + OFFB_PART), b2, (unsigned char*)(wsb + OFFB_DEC));
  attn_kernel<<<dim3(4, 16, 3), 128, 0, stream>>>(
      (const unsigned short*)(wsb + OFFB_QB), (const unsigned short*)(wsb + OFFB_KB),
      (const unsigned short*)(wsb + OFFB_VT), (const unsigned char*)(wsb + OFFB_DEC),
      (unsigned short*)(wsb + OFFB_OB));
  fc_mfma<<<dim3(16, 2, 3), 128, 0, stream>>>(wsb);
  ln_kernel<<<384, 256, 0, stream>>>((const float*)(wsb + OFFB_O2), x0, x1, x2,
                                     lng, lnb, out);
}